// Round 1
// baseline (1836.667 us; speedup 1.0000x reference)
//
#include <hip/hip_runtime.h>
#include <hip/hip_bf16.h>

#define D_MODEL 1024
#define NHEAD   16
#define HDK     64
#define SEQ     2048
#define BATCH   2

// ---------------------------------------------------------------------------
// GEMM:  Y[m][n] = sum_k X[m][k] * W[n][k]     (i.e. Y = X @ W^T)
// Block: 256 threads, 64x64 output tile, BK=16, each thread 4x4 micro-tile.
// ---------------------------------------------------------------------------
__global__ __launch_bounds__(256)
void gemm_xwt(const float* __restrict__ X, const float* __restrict__ W,
              float* __restrict__ Y, int M, int N, int K) {
    __shared__ __align__(16) float Xs[16][68];   // [k][m], padded (68*4B = 16B-aligned rows)
    __shared__ __align__(16) float Ws[16][68];   // [k][n]

    const int tx   = threadIdx.x;
    const int bm   = blockIdx.y * 64;
    const int bn   = blockIdx.x * 64;
    const int tr   = tx >> 4;          // 0..15
    const int tc   = tx & 15;          // 0..15
    const int lrow = tx >> 2;          // 0..63 staging row
    const int lk   = (tx & 3) * 4;     // staging k offset

    float acc[4][4] = {};

    for (int kt = 0; kt < K; kt += 16) {
        float4 xv = *(const float4*)(X + (size_t)(bm + lrow) * K + kt + lk);
        float4 wv = *(const float4*)(W + (size_t)(bn + lrow) * K + kt + lk);
        __syncthreads();               // previous iteration done reading LDS
        Xs[lk + 0][lrow] = xv.x; Xs[lk + 1][lrow] = xv.y;
        Xs[lk + 2][lrow] = xv.z; Xs[lk + 3][lrow] = xv.w;
        Ws[lk + 0][lrow] = wv.x; Ws[lk + 1][lrow] = wv.y;
        Ws[lk + 2][lrow] = wv.z; Ws[lk + 3][lrow] = wv.w;
        __syncthreads();
        #pragma unroll
        for (int k = 0; k < 16; ++k) {
            float4 a = *(const float4*)&Xs[k][tr * 4];
            float4 b = *(const float4*)&Ws[k][tc * 4];
            float av[4] = {a.x, a.y, a.z, a.w};
            float bv[4] = {b.x, b.y, b.z, b.w};
            #pragma unroll
            for (int i = 0; i < 4; ++i)
                #pragma unroll
                for (int j = 0; j < 4; ++j)
                    acc[i][j] += av[i] * bv[j];
        }
    }

    #pragma unroll
    for (int i = 0; i < 4; ++i) {
        float4 o = make_float4(acc[i][0], acc[i][1], acc[i][2], acc[i][3]);
        *(float4*)(Y + (size_t)(bm + tr * 4 + i) * N + bn + tc * 4) = o;
    }
}

// ---------------------------------------------------------------------------
// Flash-style causal attention.
// Grid: (S/64 q-tiles, H, B). Block: 256 threads.
// Thread t: qi = t>>2 (q-row in tile), j = t&3 (quarter: 16 k-cols / 16 d-dims).
// K-tile LDS buffer is reused to hold P after scores are consumed.
// ---------------------------------------------------------------------------
__global__ __launch_bounds__(256)
void attn_kernel(const float* __restrict__ Q, const float* __restrict__ K,
                 const float* __restrict__ V, float* __restrict__ A) {
    __shared__ __align__(16) float Qs [64][68];
    __shared__ __align__(16) float KPs[64][68];   // K tile, then P tile
    __shared__ __align__(16) float Vs [64][68];

    const int b  = blockIdx.z;
    const int h  = blockIdx.y;
    const int qt = blockIdx.x;
    const int t  = threadIdx.x;
    const int qi = t >> 2;
    const int j  = t & 3;
    const int q0 = qt * 64;
    const size_t base = (size_t)b * SEQ * D_MODEL + (size_t)h * HDK;

    // stage Q tile once
    {
        const int row = t >> 2;
        const int d0  = (t & 3) * 16;
        const float* src = Q + base + (size_t)(q0 + row) * D_MODEL + d0;
        #pragma unroll
        for (int c = 0; c < 4; ++c)
            *(float4*)&Qs[row][d0 + 4 * c] = *(const float4*)(src + 4 * c);
    }

    float m_run = -INFINITY, l_run = 0.f;
    float o_acc[16];
    #pragma unroll
    for (int i = 0; i < 16; ++i) o_acc[i] = 0.f;

    for (int kt = 0; kt <= qt; ++kt) {
        const int k0 = kt * 64;
        __syncthreads();   // previous iteration done with KPs/Vs (and Qs staged, 1st iter)
        {
            const int row = t >> 2;
            const int d0  = (t & 3) * 16;
            const float* sk = K + base + (size_t)(k0 + row) * D_MODEL + d0;
            const float* sv = V + base + (size_t)(k0 + row) * D_MODEL + d0;
            #pragma unroll
            for (int c = 0; c < 4; ++c) {
                *(float4*)&KPs[row][d0 + 4 * c] = *(const float4*)(sk + 4 * c);
                *(float4*)&Vs [row][d0 + 4 * c] = *(const float4*)(sv + 4 * c);
            }
        }
        __syncthreads();

        // scores for this thread's 16 k-columns
        float s[16];
        #pragma unroll
        for (int kk = 0; kk < 16; ++kk) {
            const int kj = j * 16 + kk;
            float a0 = 0.f, a1 = 0.f, a2 = 0.f, a3 = 0.f;
            #pragma unroll
            for (int d = 0; d < 64; d += 4) {
                float4 qv = *(const float4*)&Qs[qi][d];
                float4 kv = *(const float4*)&KPs[kj][d];
                a0 += qv.x * kv.x; a1 += qv.y * kv.y;
                a2 += qv.z * kv.z; a3 += qv.w * kv.w;
            }
            float sc = (a0 + a1 + a2 + a3) * 0.125f;  // 1/sqrt(64)
            if (k0 + kj > q0 + qi) sc = -1e30f;       // causal mask
            s[kk] = sc;
        }
        __syncthreads();   // everyone done reading K half of KPs

        // online softmax update (4 lanes per q-row cooperate via shuffle)
        float tmax = s[0];
        #pragma unroll
        for (int kk = 1; kk < 16; ++kk) tmax = fmaxf(tmax, s[kk]);
        tmax = fmaxf(tmax, __shfl_xor(tmax, 1));
        tmax = fmaxf(tmax, __shfl_xor(tmax, 2));
        const float m_new = fmaxf(m_run, tmax);
        const float alpha = __expf(m_run - m_new);
        float psum = 0.f;
        #pragma unroll
        for (int kk = 0; kk < 16; ++kk) {
            float p = __expf(s[kk] - m_new);
            s[kk] = p;
            psum += p;
        }
        psum += __shfl_xor(psum, 1);
        psum += __shfl_xor(psum, 2);
        l_run = l_run * alpha + psum;
        m_run = m_new;

        #pragma unroll
        for (int kk = 0; kk < 16; kk += 4)
            *(float4*)&KPs[qi][j * 16 + kk] =
                make_float4(s[kk], s[kk + 1], s[kk + 2], s[kk + 3]);
        #pragma unroll
        for (int i = 0; i < 16; ++i) o_acc[i] *= alpha;
        __syncthreads();   // P visible

        // O += P @ V  (thread owns d-dims j*16..j*16+15 of its q-row)
        for (int kj4 = 0; kj4 < 64; kj4 += 4) {
            float4 p4 = *(const float4*)&KPs[qi][kj4];
            float pv[4] = {p4.x, p4.y, p4.z, p4.w};
            #pragma unroll
            for (int u = 0; u < 4; ++u) {
                const float p = pv[u];
                #pragma unroll
                for (int dd = 0; dd < 16; dd += 4) {
                    float4 vv = *(const float4*)&Vs[kj4 + u][j * 16 + dd];
                    o_acc[dd + 0] += p * vv.x;
                    o_acc[dd + 1] += p * vv.y;
                    o_acc[dd + 2] += p * vv.z;
                    o_acc[dd + 3] += p * vv.w;
                }
            }
        }
    }

    const float inv_l = 1.f / l_run;
    float* dst = A + base + (size_t)(q0 + qi) * D_MODEL + j * 16;
    #pragma unroll
    for (int dd = 0; dd < 16; dd += 4)
        *(float4*)(dst + dd) = make_float4(o_acc[dd] * inv_l, o_acc[dd + 1] * inv_l,
                                           o_acc[dd + 2] * inv_l, o_acc[dd + 3] * inv_l);
}

// ---------------------------------------------------------------------------
extern "C" void kernel_launch(void* const* d_in, const int* in_sizes, int n_in,
                              void* d_out, int out_size, void* d_ws, size_t ws_size,
                              hipStream_t stream) {
    const float* q   = (const float*)d_in[0];
    const float* k   = (const float*)d_in[1];
    const float* v   = (const float*)d_in[2];
    // d_in[3]: causal mask (int32) — implemented analytically
    const float* Wq  = (const float*)d_in[4];
    const float* Wk  = (const float*)d_in[5];
    const float* Wv  = (const float*)d_in[6];
    const float* Wo  = (const float*)d_in[7];
    float* out = (float*)d_out;

    const int BS = BATCH * SEQ;            // 4096
    const size_t PLANE = (size_t)BS * D_MODEL;  // 4 Mi elements
    float* ws = (float*)d_ws;
    float* Qp = ws;
    float* Kp = ws + PLANE;
    float* Vp = ws + 2 * PLANE;
    float* Ap = ws + 3 * PLANE;

    dim3 gblk(256);
    dim3 ggrid(D_MODEL / 64, BS / 64);     // (16, 64)

    gemm_xwt<<<ggrid, gblk, 0, stream>>>(q, Wq, Qp, BS, D_MODEL, D_MODEL);
    gemm_xwt<<<ggrid, gblk, 0, stream>>>(k, Wk, Kp, BS, D_MODEL, D_MODEL);
    gemm_xwt<<<ggrid, gblk, 0, stream>>>(v, Wv, Vp, BS, D_MODEL, D_MODEL);

    attn_kernel<<<dim3(SEQ / 64, NHEAD, BATCH), 256, 0, stream>>>(Qp, Kp, Vp, Ap);

    gemm_xwt<<<ggrid, gblk, 0, stream>>>(Ap, Wo, out, BS, D_MODEL, D_MODEL);
}

// Round 2
// 452.604 us; speedup vs baseline: 4.0580x; 4.0580x over previous
//
#include <hip/hip_runtime.h>
#include <hip/hip_bf16.h>

#define D_MODEL 1024
#define NHEAD   16
#define HDK     64
#define SEQ     2048
#define BATCH   2
#define BS      (BATCH * SEQ)

typedef __attribute__((ext_vector_type(8))) short bf16x8;
typedef __attribute__((ext_vector_type(4))) float f32x4;

__device__ __forceinline__ unsigned short f2bf(float f) {
    unsigned u = __builtin_bit_cast(unsigned, f);
    u += 0x7fffu + ((u >> 16) & 1u);          // round-to-nearest-even
    return (unsigned short)(u >> 16);
}

// ---------------------------------------------------------------------------
// fp32 -> bf16 cast, 8 elements / thread
// ---------------------------------------------------------------------------
__global__ __launch_bounds__(256)
void cast_f32_bf16(const float* __restrict__ x, unsigned short* __restrict__ y, int n8) {
    int i = blockIdx.x * 256 + threadIdx.x;
    if (i >= n8) return;
    const float4* p = (const float4*)x + (size_t)i * 2;
    float4 a = p[0], b = p[1];
    ushort4 lo = make_ushort4(f2bf(a.x), f2bf(a.y), f2bf(a.z), f2bf(a.w));
    ushort4 hi = make_ushort4(f2bf(b.x), f2bf(b.y), f2bf(b.z), f2bf(b.w));
    ushort4* q = (ushort4*)y + (size_t)i * 2;
    q[0] = lo; q[1] = hi;
}

// ---------------------------------------------------------------------------
// bf16 MFMA GEMM:  Y[m][n] = sum_k X[m][k] * W[n][k]   (NT, both row-major)
// Tile: BM=128, BN=64, BK=64. 4 waves, wave w owns rows w*32..w*32+31.
// LDS rows padded to 72 bf16 (stride 36 dwords == 4 mod 32 -> uniform banks).
// ---------------------------------------------------------------------------
template <int STORE_BF16>
__global__ __launch_bounds__(256)
void gemm_bf16(const unsigned short* __restrict__ X, const unsigned short* __restrict__ W,
               void* __restrict__ Yv, int M, int N, int K) {
    __shared__ __align__(16) unsigned short Xs[128 * 72];
    __shared__ __align__(16) unsigned short Ws[64 * 72];

    const int t    = threadIdx.x;
    const int w    = t >> 6;
    const int L    = t & 63;
    const int quad = L >> 4;
    const int lm   = L & 15;
    const int bm   = blockIdx.y * 128;
    const int bn   = blockIdx.x * 64;

    f32x4 acc[2][4];
    #pragma unroll
    for (int ms = 0; ms < 2; ++ms)
        #pragma unroll
        for (int ns = 0; ns < 4; ++ns)
            acc[ms][ns] = (f32x4){0.f, 0.f, 0.f, 0.f};

    for (int kt = 0; kt < K; kt += 64) {
        __syncthreads();
        #pragma unroll
        for (int i = 0; i < 4; ++i) {                 // X: 128 rows x 64 cols
            int c = i * 256 + t, row = c >> 3, cg = c & 7;
            *(float4*)&Xs[row * 72 + cg * 8] =
                *(const float4*)(X + (size_t)(bm + row) * K + kt + cg * 8);
        }
        #pragma unroll
        for (int i = 0; i < 2; ++i) {                 // W: 64 rows x 64 cols
            int c = i * 256 + t, row = c >> 3, cg = c & 7;
            *(float4*)&Ws[row * 72 + cg * 8] =
                *(const float4*)(W + (size_t)(bn + row) * K + kt + cg * 8);
        }
        __syncthreads();

        #pragma unroll
        for (int ch = 0; ch < 2; ++ch) {
            bf16x8 af[2], bfr[4];
            #pragma unroll
            for (int ms = 0; ms < 2; ++ms)
                af[ms] = *(const bf16x8*)&Xs[(w * 32 + ms * 16 + lm) * 72 + ch * 32 + quad * 8];
            #pragma unroll
            for (int ns = 0; ns < 4; ++ns)
                bfr[ns] = *(const bf16x8*)&Ws[(ns * 16 + lm) * 72 + ch * 32 + quad * 8];
            #pragma unroll
            for (int ms = 0; ms < 2; ++ms)
                #pragma unroll
                for (int ns = 0; ns < 4; ++ns)
                    acc[ms][ns] = __builtin_amdgcn_mfma_f32_16x16x32_bf16(
                        af[ms], bfr[ns], acc[ms][ns], 0, 0, 0);
        }
    }

    #pragma unroll
    for (int ms = 0; ms < 2; ++ms)
        #pragma unroll
        for (int ns = 0; ns < 4; ++ns)
            #pragma unroll
            for (int r = 0; r < 4; ++r) {
                int row = bm + w * 32 + ms * 16 + quad * 4 + r;
                int col = bn + ns * 16 + lm;
                float v = acc[ms][ns][r];
                if (STORE_BF16)
                    ((unsigned short*)Yv)[(size_t)row * N + col] = f2bf(v);
                else
                    ((float*)Yv)[(size_t)row * N + col] = v;
            }
}

// ---------------------------------------------------------------------------
// MFMA flash attention, causal. Grid (S/64, H, B), 4 waves x 16 q-rows.
// K staged row-major [kv][d]; V staged transposed [d][kv]; P round-trips
// through a per-wave-private LDS slab (C-layout -> A-layout).
// ---------------------------------------------------------------------------
__global__ __launch_bounds__(256)
void attn_mfma(const unsigned short* __restrict__ Q, const unsigned short* __restrict__ K,
               const unsigned short* __restrict__ V, unsigned short* __restrict__ A) {
    __shared__ __align__(16) unsigned short Ks[64 * 72];
    __shared__ __align__(16) unsigned short Vt[64 * 72];
    __shared__ __align__(16) unsigned short Ps[4 * 16 * 72];

    const int t    = threadIdx.x;
    const int w    = t >> 6;
    const int L    = t & 63;
    const int quad = L >> 4;
    const int lm   = L & 15;
    const int qt   = blockIdx.x;
    const int h    = blockIdx.y;
    const int b    = blockIdx.z;
    const int q0   = qt * 64;
    const size_t hb = (size_t)b * SEQ * D_MODEL + h * HDK;

    // Q fragments (A-operand), held in registers for the whole kernel
    bf16x8 Qf0, Qf1;
    {
        const unsigned short* qp = Q + hb + (size_t)(q0 + w * 16 + lm) * D_MODEL + quad * 8;
        Qf0 = *(const bf16x8*)qp;
        Qf1 = *(const bf16x8*)(qp + 32);
    }

    f32x4 Oacc[4];
    #pragma unroll
    for (int nt = 0; nt < 4; ++nt) Oacc[nt] = (f32x4){0.f, 0.f, 0.f, 0.f};
    float m_run[4], l_run[4];
    #pragma unroll
    for (int r = 0; r < 4; ++r) { m_run[r] = -INFINITY; l_run[r] = 0.f; }

    for (int kt = 0; kt <= qt; ++kt) {
        const int k0 = kt * 64;
        __syncthreads();                                   // prev iter done with Ks/Vt
        #pragma unroll
        for (int i = 0; i < 2; ++i) {                      // K tile 64x64, row-major
            int c = i * 256 + t, row = c >> 3, cg = c & 7;
            *(float4*)&Ks[row * 72 + cg * 8] =
                *(const float4*)(K + hb + (size_t)(k0 + row) * D_MODEL + cg * 8);
        }
        #pragma unroll
        for (int i = 0; i < 2; ++i) {                      // V tile, transposed into Vt[d][kv]
            int c = i * 256 + t, row = c >> 3, d0 = (c & 7) * 8;
            bf16x8 vv = *(const bf16x8*)(V + hb + (size_t)(k0 + row) * D_MODEL + d0);
            #pragma unroll
            for (int j = 0; j < 8; ++j)
                Vt[(d0 + j) * 72 + row] = (unsigned short)vv[j];
        }
        __syncthreads();

        // ---- S = Q K^T (per wave: 16 q-rows x 64 kv) ----
        f32x4 S[4];
        #pragma unroll
        for (int ct = 0; ct < 4; ++ct) {
            bf16x8 b0 = *(const bf16x8*)&Ks[(ct * 16 + lm) * 72 + quad * 8];
            bf16x8 b1 = *(const bf16x8*)&Ks[(ct * 16 + lm) * 72 + 32 + quad * 8];
            f32x4 z = (f32x4){0.f, 0.f, 0.f, 0.f};
            z = __builtin_amdgcn_mfma_f32_16x16x32_bf16(Qf0, b0, z, 0, 0, 0);
            z = __builtin_amdgcn_mfma_f32_16x16x32_bf16(Qf1, b1, z, 0, 0, 0);
            S[ct] = z;
        }

        // scale + causal mask (diagonal tile only)
        const bool diag = (kt == qt);
        #pragma unroll
        for (int ct = 0; ct < 4; ++ct)
            #pragma unroll
            for (int r = 0; r < 4; ++r) {
                float s = S[ct][r] * 0.125f;
                if (diag && (k0 + ct * 16 + lm) > (q0 + w * 16 + quad * 4 + r))
                    s = -1e30f;
                S[ct][r] = s;
            }

        // ---- online softmax ----
        float mx[4], al[4], rs[4];
        #pragma unroll
        for (int r = 0; r < 4; ++r) {
            float m = fmaxf(fmaxf(S[0][r], S[1][r]), fmaxf(S[2][r], S[3][r]));
            m = fmaxf(m, __shfl_xor(m, 1));
            m = fmaxf(m, __shfl_xor(m, 2));
            m = fmaxf(m, __shfl_xor(m, 4));
            m = fmaxf(m, __shfl_xor(m, 8));
            mx[r] = m;
        }
        #pragma unroll
        for (int r = 0; r < 4; ++r) {
            float mnew = fmaxf(m_run[r], mx[r]);
            al[r] = __expf(m_run[r] - mnew);
            m_run[r] = mnew;
        }
        #pragma unroll
        for (int ct = 0; ct < 4; ++ct)
            #pragma unroll
            for (int r = 0; r < 4; ++r)
                S[ct][r] = __expf(S[ct][r] - m_run[r]);
        #pragma unroll
        for (int r = 0; r < 4; ++r) {
            float s = S[0][r] + S[1][r] + S[2][r] + S[3][r];
            s += __shfl_xor(s, 1);
            s += __shfl_xor(s, 2);
            s += __shfl_xor(s, 4);
            s += __shfl_xor(s, 8);
            rs[r] = s;
            l_run[r] = l_run[r] * al[r] + rs[r];
        }

        // ---- P: C-layout -> LDS -> A-layout (wave-private slab, no barrier) ----
        #pragma unroll
        for (int ct = 0; ct < 4; ++ct)
            #pragma unroll
            for (int r = 0; r < 4; ++r)
                Ps[(w * 16 + quad * 4 + r) * 72 + ct * 16 + lm] = f2bf(S[ct][r]);
        bf16x8 Pa0 = *(const bf16x8*)&Ps[(w * 16 + lm) * 72 + quad * 8];
        bf16x8 Pa1 = *(const bf16x8*)&Ps[(w * 16 + lm) * 72 + 32 + quad * 8];

        // ---- O = O*alpha + P V ----
        #pragma unroll
        for (int nt = 0; nt < 4; ++nt) {
            bf16x8 v0 = *(const bf16x8*)&Vt[(nt * 16 + lm) * 72 + quad * 8];
            bf16x8 v1 = *(const bf16x8*)&Vt[(nt * 16 + lm) * 72 + 32 + quad * 8];
            f32x4 o = Oacc[nt];
            #pragma unroll
            for (int r = 0; r < 4; ++r) o[r] *= al[r];
            o = __builtin_amdgcn_mfma_f32_16x16x32_bf16(Pa0, v0, o, 0, 0, 0);
            o = __builtin_amdgcn_mfma_f32_16x16x32_bf16(Pa1, v1, o, 0, 0, 0);
            Oacc[nt] = o;
        }
    }

    // epilogue: O / l, bf16 store
    #pragma unroll
    for (int nt = 0; nt < 4; ++nt)
        #pragma unroll
        for (int r = 0; r < 4; ++r) {
            int qrow = q0 + w * 16 + quad * 4 + r;
            float v = Oacc[nt][r] / l_run[r];
            A[hb + (size_t)qrow * D_MODEL + nt * 16 + lm] = f2bf(v);
        }
}

// ---------------------------------------------------------------------------
extern "C" void kernel_launch(void* const* d_in, const int* in_sizes, int n_in,
                              void* d_out, int out_size, void* d_ws, size_t ws_size,
                              hipStream_t stream) {
    const float* q  = (const float*)d_in[0];
    const float* k  = (const float*)d_in[1];
    const float* v  = (const float*)d_in[2];
    const float* Wq = (const float*)d_in[4];
    const float* Wk = (const float*)d_in[5];
    const float* Wv = (const float*)d_in[6];
    const float* Wo = (const float*)d_in[7];
    float* out = (float*)d_out;

    char* ws = (char*)d_ws;
    const size_t MB = 1024 * 1024;
    unsigned short* qb  = (unsigned short*)(ws + 0 * MB);    // 8 MB each
    unsigned short* kb  = (unsigned short*)(ws + 8 * MB);
    unsigned short* vb  = (unsigned short*)(ws + 16 * MB);
    unsigned short* wqb = (unsigned short*)(ws + 24 * MB);   // 2 MB each
    unsigned short* wkb = (unsigned short*)(ws + 26 * MB);
    unsigned short* wvb = (unsigned short*)(ws + 28 * MB);
    unsigned short* wob = (unsigned short*)(ws + 30 * MB);
    unsigned short* Qp  = (unsigned short*)(ws + 32 * MB);   // 8 MB each
    unsigned short* Kp  = (unsigned short*)(ws + 40 * MB);
    unsigned short* Vp  = (unsigned short*)(ws + 48 * MB);
    unsigned short* Ap  = (unsigned short*)(ws + 56 * MB);

    const int nX8 = BS * D_MODEL / 8;        // 524288
    const int nW8 = D_MODEL * D_MODEL / 8;   // 131072
    cast_f32_bf16<<<nX8 / 256, 256, 0, stream>>>(q, qb, nX8);
    cast_f32_bf16<<<nX8 / 256, 256, 0, stream>>>(k, kb, nX8);
    cast_f32_bf16<<<nX8 / 256, 256, 0, stream>>>(v, vb, nX8);
    cast_f32_bf16<<<nW8 / 256, 256, 0, stream>>>(Wq, wqb, nW8);
    cast_f32_bf16<<<nW8 / 256, 256, 0, stream>>>(Wk, wkb, nW8);
    cast_f32_bf16<<<nW8 / 256, 256, 0, stream>>>(Wv, wvb, nW8);
    cast_f32_bf16<<<nW8 / 256, 256, 0, stream>>>(Wo, wob, nW8);

    dim3 ggrid(D_MODEL / 64, BS / 128);      // (16, 32)
    gemm_bf16<1><<<ggrid, 256, 0, stream>>>(qb, wqb, Qp, BS, D_MODEL, D_MODEL);
    gemm_bf16<1><<<ggrid, 256, 0, stream>>>(kb, wkb, Kp, BS, D_MODEL, D_MODEL);
    gemm_bf16<1><<<ggrid, 256, 0, stream>>>(vb, wvb, Vp, BS, D_MODEL, D_MODEL);

    attn_mfma<<<dim3(SEQ / 64, NHEAD, BATCH), 256, 0, stream>>>(Qp, Kp, Vp, Ap);

    gemm_bf16<0><<<ggrid, 256, 0, stream>>>(Ap, wob, out, BS, D_MODEL, D_MODEL);
}

// Round 3
// 286.341 us; speedup vs baseline: 6.4143x; 1.5806x over previous
//
#include <hip/hip_runtime.h>
#include <hip/hip_bf16.h>

#define D_MODEL 1024
#define NHEAD   16
#define HDK     64
#define SEQ     2048
#define BATCH   2
#define BS      (BATCH * SEQ)

typedef __attribute__((ext_vector_type(8))) short bf16x8;
typedef __attribute__((ext_vector_type(4))) float f32x4;

__device__ __forceinline__ unsigned short f2bf(float f) {
    unsigned u = __builtin_bit_cast(unsigned, f);
    u += 0x7fffu + ((u >> 16) & 1u);          // round-to-nearest-even
    return (unsigned short)(u >> 16);
}

typedef const void __attribute__((address_space(1))) gas_void;
typedef void __attribute__((address_space(3))) las_void;

// async global->LDS, 16B per lane. LDS dest is wave-uniform base + lane*16.
__device__ __forceinline__ void gll16(const void* g, void* l) {
    __builtin_amdgcn_global_load_lds((gas_void*)g, (las_void*)l, 16, 0, 0);
}

// ---------------------------------------------------------------------------
// casts fp32 -> bf16 (8 elem / thread); blockIdx.y selects the tensor
// ---------------------------------------------------------------------------
__device__ __forceinline__ void cast_body(const float* __restrict__ src,
                                          unsigned short* __restrict__ dst, int i) {
    const float4* p = (const float4*)src + (size_t)i * 2;
    float4 a = p[0], b = p[1];
    ushort4 lo = make_ushort4(f2bf(a.x), f2bf(a.y), f2bf(a.z), f2bf(a.w));
    ushort4 hi = make_ushort4(f2bf(b.x), f2bf(b.y), f2bf(b.z), f2bf(b.w));
    ushort4* q = (ushort4*)dst + (size_t)i * 2;
    q[0] = lo; q[1] = hi;
}

__global__ __launch_bounds__(256)
void cast_act(const float* a, const float* b, const float* c,
              unsigned short* oa, unsigned short* ob, unsigned short* oc, int n8) {
    int i = blockIdx.x * 256 + threadIdx.x;
    if (i >= n8) return;
    const float* s = blockIdx.y == 0 ? a : blockIdx.y == 1 ? b : c;
    unsigned short* d = blockIdx.y == 0 ? oa : blockIdx.y == 1 ? ob : oc;
    cast_body(s, d, i);
}

__global__ __launch_bounds__(256)
void cast_wt(const float* a, const float* b, const float* c, const float* dd,
             unsigned short* oa, unsigned short* ob, unsigned short* oc, unsigned short* od, int n8) {
    int i = blockIdx.x * 256 + threadIdx.x;
    if (i >= n8) return;
    const float* s = blockIdx.y == 0 ? a : blockIdx.y == 1 ? b : blockIdx.y == 2 ? c : dd;
    unsigned short* d = blockIdx.y == 0 ? oa : blockIdx.y == 1 ? ob : blockIdx.y == 2 ? oc : od;
    cast_body(s, d, i);
}

// ---------------------------------------------------------------------------
// Shared GEMM K-loop: Y = X @ W^T, BM=128 BN=64 BK=64, 4 waves.
// global_load_lds staging into unpadded LDS; XOR swizzle (slot = kg ^ (row&7))
// applied on the global gather so b128 fragment reads are bank-uniform.
// ---------------------------------------------------------------------------
__device__ __forceinline__ void gemm_kloop(const unsigned short* __restrict__ X,
                                           const unsigned short* __restrict__ W,
                                           unsigned short* As, unsigned short* Bs,
                                           int bm, int bn, f32x4 acc[2][4]) {
    const int t    = threadIdx.x;
    const int w    = t >> 6;
    const int L    = t & 63;
    const int quad = L >> 4;
    const int lm   = L & 15;
    const int r8   = L >> 3;           // row within 8-row chunk
    const int sl   = L & 7;            // lds slot within row
    const int xcol = ((sl ^ r8) & 7) * 8;   // swizzled global k-group

    for (int kt = 0; kt < D_MODEL; kt += 64) {
        __syncthreads();
        #pragma unroll
        for (int i = 0; i < 4; ++i) {       // A: 128x64 = 16 chunks of 1KB
            int c = w * 4 + i;
            gll16(X + (size_t)(bm + c * 8 + r8) * D_MODEL + kt + xcol, &As[c * 512]);
        }
        #pragma unroll
        for (int i = 0; i < 2; ++i) {       // B: 64x64 = 8 chunks
            int c = w * 2 + i;
            gll16(W + (size_t)(bn + c * 8 + r8) * D_MODEL + kt + xcol, &Bs[c * 512]);
        }
        __syncthreads();                    // vmcnt(0) drain -> LDS ready

        #pragma unroll
        for (int ch = 0; ch < 2; ++ch) {
            bf16x8 af[2], bfr[4];
            #pragma unroll
            for (int ms = 0; ms < 2; ++ms) {
                int row = w * 32 + ms * 16 + lm;
                af[ms] = *(const bf16x8*)&As[row * 64 + (((ch * 4 + quad) ^ (row & 7)) * 8)];
            }
            #pragma unroll
            for (int ns = 0; ns < 4; ++ns) {
                int row = ns * 16 + lm;
                bfr[ns] = *(const bf16x8*)&Bs[row * 64 + (((ch * 4 + quad) ^ (row & 7)) * 8)];
            }
            #pragma unroll
            for (int ms = 0; ms < 2; ++ms)
                #pragma unroll
                for (int ns = 0; ns < 4; ++ns)
                    acc[ms][ns] = __builtin_amdgcn_mfma_f32_16x16x32_bf16(
                        af[ms], bfr[ns], acc[ms][ns], 0, 0, 0);
        }
    }
}

// ---------------------------------------------------------------------------
// Fused Q/K/V projections. z=0: Q (scaled by 1/8, row-major), z=1: K
// (row-major), z=2: V stored TRANSPOSED per head: VT[(b*16+h)*64+d][s].
// ---------------------------------------------------------------------------
__global__ __launch_bounds__(256)
void proj_gemm(const unsigned short* __restrict__ qx, const unsigned short* __restrict__ kx,
               const unsigned short* __restrict__ vx, const unsigned short* __restrict__ wq,
               const unsigned short* __restrict__ wk, const unsigned short* __restrict__ wv,
               unsigned short* __restrict__ Qp, unsigned short* __restrict__ Kp,
               unsigned short* __restrict__ VT) {
    __shared__ __align__(16) unsigned short As[128 * 64];
    __shared__ __align__(16) unsigned short Bs[64 * 64];

    const int p = blockIdx.z;
    const unsigned short* X = p == 0 ? qx : p == 1 ? kx : vx;
    const unsigned short* W = p == 0 ? wq : p == 1 ? wk : wv;
    const int bm = blockIdx.y * 128, bn = blockIdx.x * 64;

    f32x4 acc[2][4];
    #pragma unroll
    for (int ms = 0; ms < 2; ++ms)
        #pragma unroll
        for (int ns = 0; ns < 4; ++ns)
            acc[ms][ns] = (f32x4){0.f, 0.f, 0.f, 0.f};

    gemm_kloop(X, W, As, Bs, bm, bn, acc);

    const int t = threadIdx.x, w = t >> 6, L = t & 63, quad = L >> 4, lm = L & 15;
    if (p == 2) {
        // transposed store: lane holds 4 consecutive s for fixed d -> ushort4
        const int b  = bm >> 11;                 // bm / SEQ
        const int h  = blockIdx.x;               // bn / 64
        const int s0 = (bm & (SEQ - 1));
        #pragma unroll
        for (int ms = 0; ms < 2; ++ms)
            #pragma unroll
            for (int ns = 0; ns < 4; ++ns) {
                int d = ns * 16 + lm;
                ushort4 pk = make_ushort4(f2bf(acc[ms][ns][0]), f2bf(acc[ms][ns][1]),
                                          f2bf(acc[ms][ns][2]), f2bf(acc[ms][ns][3]));
                *(ushort4*)&VT[((size_t)((b * NHEAD + h) * HDK + d)) * SEQ +
                               s0 + w * 32 + ms * 16 + quad * 4] = pk;
            }
    } else {
        unsigned short* Y = p == 0 ? Qp : Kp;
        const float scl = p == 0 ? 0.125f : 1.0f;   // fold 1/sqrt(64) into Q
        #pragma unroll
        for (int ms = 0; ms < 2; ++ms)
            #pragma unroll
            for (int ns = 0; ns < 4; ++ns)
                #pragma unroll
                for (int r = 0; r < 4; ++r)
                    Y[(size_t)(bm + w * 32 + ms * 16 + quad * 4 + r) * D_MODEL +
                      bn + ns * 16 + lm] = f2bf(acc[ms][ns][r] * scl);
    }
}

// ---------------------------------------------------------------------------
// Final GEMM: out(fp32) = Ap @ Wo^T
// ---------------------------------------------------------------------------
__global__ __launch_bounds__(256)
void out_gemm(const unsigned short* __restrict__ X, const unsigned short* __restrict__ W,
              float* __restrict__ Y) {
    __shared__ __align__(16) unsigned short As[128 * 64];
    __shared__ __align__(16) unsigned short Bs[64 * 64];
    const int bm = blockIdx.y * 128, bn = blockIdx.x * 64;

    f32x4 acc[2][4];
    #pragma unroll
    for (int ms = 0; ms < 2; ++ms)
        #pragma unroll
        for (int ns = 0; ns < 4; ++ns)
            acc[ms][ns] = (f32x4){0.f, 0.f, 0.f, 0.f};

    gemm_kloop(X, W, As, Bs, bm, bn, acc);

    const int t = threadIdx.x, w = t >> 6, L = t & 63, quad = L >> 4, lm = L & 15;
    #pragma unroll
    for (int ms = 0; ms < 2; ++ms)
        #pragma unroll
        for (int ns = 0; ns < 4; ++ns)
            #pragma unroll
            for (int r = 0; r < 4; ++r)
                Y[(size_t)(bm + w * 32 + ms * 16 + quad * 4 + r) * D_MODEL +
                  bn + ns * 16 + lm] = acc[ms][ns][r];
}

// ---------------------------------------------------------------------------
// Flash attention, causal. Grid (S/128, H, B), 512 threads = 8 waves, each
// wave owns 16 q-rows. K row-major, V pre-transposed (VT). Register-prefetch
// software pipeline hides global latency behind the compute phase.
// Q is pre-scaled by 1/8 in the projection.
// ---------------------------------------------------------------------------
__global__ __launch_bounds__(512, 4)
void attn_mfma(const unsigned short* __restrict__ Q, const unsigned short* __restrict__ K,
               const unsigned short* __restrict__ VT, unsigned short* __restrict__ A) {
    __shared__ __align__(16) unsigned short Ks[64 * 72];      // [kv][d]
    __shared__ __align__(16) unsigned short Vs[64 * 72];      // [d][kv]  (V^T tile)
    __shared__ __align__(16) unsigned short Ps[8 * 16 * 72];  // per-wave P slabs

    const int t    = threadIdx.x;
    const int w    = t >> 6;
    const int L    = t & 63;
    const int quad = L >> 4;
    const int lm   = L & 15;
    const int qt   = blockIdx.x;
    const int h    = blockIdx.y;
    const int b    = blockIdx.z;
    const int q0   = qt * 128;
    const size_t hb  = (size_t)b * SEQ * D_MODEL + h * HDK;
    const size_t vhb = (size_t)(b * NHEAD + h) * HDK;

    // Q fragments (A-operand), registers for the whole kernel
    bf16x8 Qf0, Qf1;
    {
        const unsigned short* qp = Q + hb + (size_t)(q0 + w * 16 + lm) * D_MODEL + quad * 8;
        Qf0 = *(const bf16x8*)qp;
        Qf1 = *(const bf16x8*)(qp + 32);
    }

    f32x4 Oacc[4];
    #pragma unroll
    for (int nt = 0; nt < 4; ++nt) Oacc[nt] = (f32x4){0.f, 0.f, 0.f, 0.f};
    float m_run[4], l_run[4];
    #pragma unroll
    for (int r = 0; r < 4; ++r) { m_run[r] = -INFINITY; l_run[r] = 0.f; }

    const int srow = t >> 3;             // 0..63 (kv row for K / d row for VT)
    const int sg   = (t & 7) * 8;        // 16B chunk within row
    const unsigned short* kp = K + hb + (size_t)srow * D_MODEL + sg;
    const unsigned short* vp = VT + (vhb + srow) * SEQ + sg;
    const int ktmax = 2 * qt + 1;

    float4 kreg = *(const float4*)kp;    // tile 0
    float4 vreg = *(const float4*)vp;

    unsigned short* ps = &Ps[w * 16 * 72];

    for (int kt = 0; kt <= ktmax; ++kt) {
        const int k0 = kt * 64;
        __syncthreads();                               // prev compute done with LDS
        *(float4*)&Ks[srow * 72 + sg] = kreg;
        *(float4*)&Vs[srow * 72 + sg] = vreg;
        if (kt < ktmax) {                              // prefetch next tile
            kreg = *(const float4*)(kp + (size_t)(k0 + 64) * D_MODEL);
            vreg = *(const float4*)(vp + k0 + 64);
        }
        __syncthreads();                               // LDS ready

        if (k0 > q0 + w * 16 + 15) continue;           // fully masked for this wave

        // ---- S = Q K^T (16 q-rows x 64 kv) ----
        f32x4 S[4];
        #pragma unroll
        for (int ct = 0; ct < 4; ++ct) {
            bf16x8 k0f = *(const bf16x8*)&Ks[(ct * 16 + lm) * 72 + quad * 8];
            bf16x8 k1f = *(const bf16x8*)&Ks[(ct * 16 + lm) * 72 + 32 + quad * 8];
            f32x4 z = (f32x4){0.f, 0.f, 0.f, 0.f};
            z = __builtin_amdgcn_mfma_f32_16x16x32_bf16(Qf0, k0f, z, 0, 0, 0);
            z = __builtin_amdgcn_mfma_f32_16x16x32_bf16(Qf1, k1f, z, 0, 0, 0);
            S[ct] = z;
        }

        // causal mask (only diag-straddling tiles)
        if (k0 + 63 > q0 + w * 16) {
            #pragma unroll
            for (int ct = 0; ct < 4; ++ct)
                #pragma unroll
                for (int r = 0; r < 4; ++r)
                    if ((k0 + ct * 16 + lm) > (q0 + w * 16 + quad * 4 + r))
                        S[ct][r] = -1e30f;
        }

        // ---- online softmax ----
        float al[4];
        #pragma unroll
        for (int r = 0; r < 4; ++r) {
            float m = fmaxf(fmaxf(S[0][r], S[1][r]), fmaxf(S[2][r], S[3][r]));
            m = fmaxf(m, __shfl_xor(m, 1));
            m = fmaxf(m, __shfl_xor(m, 2));
            m = fmaxf(m, __shfl_xor(m, 4));
            m = fmaxf(m, __shfl_xor(m, 8));
            float mnew = fmaxf(m_run[r], m);
            al[r] = __expf(m_run[r] - mnew);
            m_run[r] = mnew;
        }
        #pragma unroll
        for (int ct = 0; ct < 4; ++ct)
            #pragma unroll
            for (int r = 0; r < 4; ++r)
                S[ct][r] = __expf(S[ct][r] - m_run[r]);
        #pragma unroll
        for (int r = 0; r < 4; ++r) {
            float s = (S[0][r] + S[1][r]) + (S[2][r] + S[3][r]);
            s += __shfl_xor(s, 1);
            s += __shfl_xor(s, 2);
            s += __shfl_xor(s, 4);
            s += __shfl_xor(s, 8);
            l_run[r] = l_run[r] * al[r] + s;
        }

        // ---- P: C-layout -> wave-private LDS slab -> A-layout ----
        #pragma unroll
        for (int ct = 0; ct < 4; ++ct)
            #pragma unroll
            for (int r = 0; r < 4; ++r)
                ps[(quad * 4 + r) * 72 + ct * 16 + lm] = f2bf(S[ct][r]);
        bf16x8 Pa0 = *(const bf16x8*)&ps[lm * 72 + quad * 8];
        bf16x8 Pa1 = *(const bf16x8*)&ps[lm * 72 + 32 + quad * 8];

        // ---- O = O*alpha + P V ----
        #pragma unroll
        for (int nt = 0; nt < 4; ++nt) {
            bf16x8 v0 = *(const bf16x8*)&Vs[(nt * 16 + lm) * 72 + quad * 8];
            bf16x8 v1 = *(const bf16x8*)&Vs[(nt * 16 + lm) * 72 + 32 + quad * 8];
            f32x4 o = Oacc[nt];
            #pragma unroll
            for (int r = 0; r < 4; ++r) o[r] *= al[r];
            o = __builtin_amdgcn_mfma_f32_16x16x32_bf16(Pa0, v0, o, 0, 0, 0);
            o = __builtin_amdgcn_mfma_f32_16x16x32_bf16(Pa1, v1, o, 0, 0, 0);
            Oacc[nt] = o;
        }
    }

    #pragma unroll
    for (int nt = 0; nt < 4; ++nt)
        #pragma unroll
        for (int r = 0; r < 4; ++r) {
            float v = Oacc[nt][r] / l_run[r];
            A[hb + (size_t)(q0 + w * 16 + quad * 4 + r) * D_MODEL + nt * 16 + lm] = f2bf(v);
        }
}

// ---------------------------------------------------------------------------
extern "C" void kernel_launch(void* const* d_in, const int* in_sizes, int n_in,
                              void* d_out, int out_size, void* d_ws, size_t ws_size,
                              hipStream_t stream) {
    const float* q  = (const float*)d_in[0];
    const float* k  = (const float*)d_in[1];
    const float* v  = (const float*)d_in[2];
    const float* Wq = (const float*)d_in[4];
    const float* Wk = (const float*)d_in[5];
    const float* Wv = (const float*)d_in[6];
    const float* Wo = (const float*)d_in[7];
    float* out = (float*)d_out;

    char* ws = (char*)d_ws;
    const size_t MB = 1024 * 1024;
    unsigned short* qb  = (unsigned short*)(ws + 0 * MB);
    unsigned short* kb  = (unsigned short*)(ws + 8 * MB);
    unsigned short* vb  = (unsigned short*)(ws + 16 * MB);
    unsigned short* wqb = (unsigned short*)(ws + 24 * MB);
    unsigned short* wkb = (unsigned short*)(ws + 26 * MB);
    unsigned short* wvb = (unsigned short*)(ws + 28 * MB);
    unsigned short* wob = (unsigned short*)(ws + 30 * MB);
    unsigned short* Qp  = (unsigned short*)(ws + 32 * MB);
    unsigned short* Kp  = (unsigned short*)(ws + 40 * MB);
    unsigned short* VTp = (unsigned short*)(ws + 48 * MB);
    unsigned short* Ap  = (unsigned short*)(ws + 56 * MB);

    const int nX8 = BS * D_MODEL / 8;        // 524288
    const int nW8 = D_MODEL * D_MODEL / 8;   // 131072
    cast_act<<<dim3(nX8 / 256, 3), 256, 0, stream>>>(q, k, v, qb, kb, vb, nX8);
    cast_wt <<<dim3(nW8 / 256, 4), 256, 0, stream>>>(Wq, Wk, Wv, Wo, wqb, wkb, wvb, wob, nW8);

    proj_gemm<<<dim3(D_MODEL / 64, BS / 128, 3), 256, 0, stream>>>(
        qb, kb, vb, wqb, wkb, wvb, Qp, Kp, VTp);

    attn_mfma<<<dim3(SEQ / 128, NHEAD, BATCH), 512, 0, stream>>>(Qp, Kp, VTp, Ap);

    out_gemm<<<dim3(D_MODEL / 64, BS / 128), 256, 0, stream>>>(Ap, wob, out);
}

// Round 4
// 249.748 us; speedup vs baseline: 7.3541x; 1.1465x over previous
//
#include <hip/hip_runtime.h>
#include <hip/hip_bf16.h>

#define D_MODEL 1024
#define NHEAD   16
#define HDK     64
#define SEQ     2048
#define BATCH   2
#define BS      (BATCH * SEQ)

typedef __attribute__((ext_vector_type(8))) short bf16x8;
typedef __attribute__((ext_vector_type(4))) float f32x4;

__device__ __forceinline__ unsigned short f2bf(float f) {
    unsigned u = __builtin_bit_cast(unsigned, f);
    u += 0x7fffu + ((u >> 16) & 1u);          // round-to-nearest-even
    return (unsigned short)(u >> 16);
}

typedef const void __attribute__((address_space(1))) gas_void;
typedef void __attribute__((address_space(3))) las_void;

__device__ __forceinline__ void gll16(const void* g, void* l) {
    __builtin_amdgcn_global_load_lds((gas_void*)g, (las_void*)l, 16, 0, 0);
}

// ---------------------------------------------------------------------------
// fp32 -> bf16 casts
// ---------------------------------------------------------------------------
__device__ __forceinline__ void cast_body(const float* __restrict__ src,
                                          unsigned short* __restrict__ dst, int i) {
    const float4* p = (const float4*)src + (size_t)i * 2;
    float4 a = p[0], b = p[1];
    ushort4 lo = make_ushort4(f2bf(a.x), f2bf(a.y), f2bf(a.z), f2bf(a.w));
    ushort4 hi = make_ushort4(f2bf(b.x), f2bf(b.y), f2bf(b.z), f2bf(b.w));
    ushort4* q = (ushort4*)dst + (size_t)i * 2;
    q[0] = lo; q[1] = hi;
}

__global__ __launch_bounds__(256)
void cast_act(const float* a, const float* b, const float* c,
              unsigned short* oa, unsigned short* ob, unsigned short* oc, int n8) {
    int i = blockIdx.x * 256 + threadIdx.x;
    if (i >= n8) return;
    const float* s = blockIdx.y == 0 ? a : blockIdx.y == 1 ? b : c;
    unsigned short* d = blockIdx.y == 0 ? oa : blockIdx.y == 1 ? ob : oc;
    cast_body(s, d, i);
}

__global__ __launch_bounds__(256)
void cast_wt(const float* a, const float* b, const float* c, const float* dd,
             unsigned short* oa, unsigned short* ob, unsigned short* oc, unsigned short* od, int n8) {
    int i = blockIdx.x * 256 + threadIdx.x;
    if (i >= n8) return;
    const float* s = blockIdx.y == 0 ? a : blockIdx.y == 1 ? b : blockIdx.y == 2 ? c : dd;
    unsigned short* d = blockIdx.y == 0 ? oa : blockIdx.y == 1 ? ob : blockIdx.y == 2 ? oc : od;
    cast_body(s, d, i);
}

// ---------------------------------------------------------------------------
// GEMM K-loop: Y = X @ W^T, BM=128 BN=128 BK=64, 256 thr, wave w -> 64x64
// quadrant (wr=(w>>1)*64, wc=(w&1)*64). gll16 staging, XOR-swizzled LDS.
// ---------------------------------------------------------------------------
__device__ __forceinline__ void gemm_kloop128(const unsigned short* __restrict__ X,
                                              const unsigned short* __restrict__ W,
                                              unsigned short* As, unsigned short* Bs,
                                              int bm, int bn, f32x4 acc[4][4]) {
    const int t    = threadIdx.x;
    const int w    = t >> 6;
    const int L    = t & 63;
    const int quad = L >> 4;
    const int lm   = L & 15;
    const int r8   = L >> 3;
    const int sl   = L & 7;
    const int xcol = ((sl ^ r8) & 7) * 8;
    const int wr   = (w >> 1) * 64;
    const int wc   = (w & 1) * 64;

    for (int kt = 0; kt < D_MODEL; kt += 64) {
        __syncthreads();
        #pragma unroll
        for (int i = 0; i < 4; ++i) {            // A: 128x64 = 16 chunks of 8 rows
            int c = w * 4 + i;
            gll16(X + (size_t)(bm + c * 8 + r8) * D_MODEL + kt + xcol, &As[c * 512]);
        }
        #pragma unroll
        for (int i = 0; i < 4; ++i) {            // B: 128x64
            int c = w * 4 + i;
            gll16(W + (size_t)(bn + c * 8 + r8) * D_MODEL + kt + xcol, &Bs[c * 512]);
        }
        __syncthreads();

        #pragma unroll
        for (int ch = 0; ch < 2; ++ch) {
            bf16x8 af[4], bfr[4];
            #pragma unroll
            for (int ms = 0; ms < 4; ++ms) {
                int row = wr + ms * 16 + lm;
                af[ms] = *(const bf16x8*)&As[row * 64 + (((ch * 4 + quad) ^ (row & 7)) * 8)];
            }
            #pragma unroll
            for (int ns = 0; ns < 4; ++ns) {
                int row = wc + ns * 16 + lm;
                bfr[ns] = *(const bf16x8*)&Bs[row * 64 + (((ch * 4 + quad) ^ (row & 7)) * 8)];
            }
            #pragma unroll
            for (int ms = 0; ms < 4; ++ms)
                #pragma unroll
                for (int ns = 0; ns < 4; ++ns)
                    acc[ms][ns] = __builtin_amdgcn_mfma_f32_16x16x32_bf16(
                        af[ms], bfr[ns], acc[ms][ns], 0, 0, 0);
        }
    }
}

// ---------------------------------------------------------------------------
// Fused Q/K/V projections. z=0: Q (x0.125, row-major), z=1: K (row-major),
// z=2: V transposed per head: VT[(b*16+h)*64+d][s].
// ---------------------------------------------------------------------------
__global__ __launch_bounds__(256, 3)
void proj_gemm(const unsigned short* __restrict__ qx, const unsigned short* __restrict__ kx,
               const unsigned short* __restrict__ vx, const unsigned short* __restrict__ wq,
               const unsigned short* __restrict__ wk, const unsigned short* __restrict__ wv,
               unsigned short* __restrict__ Qp, unsigned short* __restrict__ Kp,
               unsigned short* __restrict__ VT) {
    __shared__ __align__(16) unsigned short As[128 * 64];
    __shared__ __align__(16) unsigned short Bs[128 * 64];

    const int p = blockIdx.z;
    const unsigned short* X = p == 0 ? qx : p == 1 ? kx : vx;
    const unsigned short* W = p == 0 ? wq : p == 1 ? wk : wv;
    const int bm = blockIdx.y * 128, bn = blockIdx.x * 128;

    f32x4 acc[4][4];
    #pragma unroll
    for (int ms = 0; ms < 4; ++ms)
        #pragma unroll
        for (int ns = 0; ns < 4; ++ns)
            acc[ms][ns] = (f32x4){0.f, 0.f, 0.f, 0.f};

    gemm_kloop128(X, W, As, Bs, bm, bn, acc);

    const int t = threadIdx.x, w = t >> 6, L = t & 63, quad = L >> 4, lm = L & 15;
    const int wr = (w >> 1) * 64, wc = (w & 1) * 64;
    if (p == 2) {
        const int b   = bm >> 11;
        const int s_in = (bm & (SEQ - 1)) + wr;
        #pragma unroll
        for (int ms = 0; ms < 4; ++ms)
            #pragma unroll
            for (int ns = 0; ns < 4; ++ns) {
                int dg = bn + wc + ns * 16 + lm;        // global output col
                int h  = dg >> 6, d = dg & 63;
                ushort4 pk = make_ushort4(f2bf(acc[ms][ns][0]), f2bf(acc[ms][ns][1]),
                                          f2bf(acc[ms][ns][2]), f2bf(acc[ms][ns][3]));
                *(ushort4*)&VT[((size_t)((b * NHEAD + h) * HDK + d)) * SEQ +
                               s_in + ms * 16 + quad * 4] = pk;
            }
    } else {
        unsigned short* Y = p == 0 ? Qp : Kp;
        const float scl = p == 0 ? 0.125f : 1.0f;
        #pragma unroll
        for (int ms = 0; ms < 4; ++ms)
            #pragma unroll
            for (int ns = 0; ns < 4; ++ns)
                #pragma unroll
                for (int r = 0; r < 4; ++r)
                    Y[(size_t)(bm + wr + ms * 16 + quad * 4 + r) * D_MODEL +
                      bn + wc + ns * 16 + lm] = f2bf(acc[ms][ns][r] * scl);
    }
}

__global__ __launch_bounds__(256, 3)
void out_gemm(const unsigned short* __restrict__ X, const unsigned short* __restrict__ W,
              float* __restrict__ Y) {
    __shared__ __align__(16) unsigned short As[128 * 64];
    __shared__ __align__(16) unsigned short Bs[128 * 64];
    const int bm = blockIdx.y * 128, bn = blockIdx.x * 128;

    f32x4 acc[4][4];
    #pragma unroll
    for (int ms = 0; ms < 4; ++ms)
        #pragma unroll
        for (int ns = 0; ns < 4; ++ns)
            acc[ms][ns] = (f32x4){0.f, 0.f, 0.f, 0.f};

    gemm_kloop128(X, W, As, Bs, bm, bn, acc);

    const int t = threadIdx.x, w = t >> 6, L = t & 63, quad = L >> 4, lm = L & 15;
    const int wr = (w >> 1) * 64, wc = (w & 1) * 64;
    #pragma unroll
    for (int ms = 0; ms < 4; ++ms)
        #pragma unroll
        for (int ns = 0; ns < 4; ++ns)
            #pragma unroll
            for (int r = 0; r < 4; ++r)
                Y[(size_t)(bm + wr + ms * 16 + quad * 4 + r) * D_MODEL +
                  bn + wc + ns * 16 + lm] = acc[ms][ns][r];
}

// ---------------------------------------------------------------------------
// Flash attention, causal, S^T formulation. Grid (32,16,2), 256 thr = 4 waves
// x 16 q-rows. qt = 31 - blockIdx.x (longest first). Lane owns ONE q-row
// (q = lm): scalar m/l softmax state, 2-level shuffles. O^T accumulator;
// epilogue transposes via the freed P slab for coalesced stores.
// ---------------------------------------------------------------------------
__global__ __launch_bounds__(256, 5)
void attn_mfma(const unsigned short* __restrict__ Q, const unsigned short* __restrict__ K,
               const unsigned short* __restrict__ VT, unsigned short* __restrict__ A) {
    __shared__ __align__(16) unsigned short Ks[64 * 72];      // [kv][d]
    __shared__ __align__(16) unsigned short Vs[64 * 72];      // [d][kv]
    __shared__ __align__(16) unsigned short Ps[4 * 16 * 72];  // per-wave P^T slabs [q][kv]

    const int t    = threadIdx.x;
    const int w    = t >> 6;
    const int L    = t & 63;
    const int quad = L >> 4;
    const int lm   = L & 15;
    const int qt   = 31 - blockIdx.x;          // longest blocks dispatch first
    const int h    = blockIdx.y;
    const int b    = blockIdx.z;
    const int q0   = qt * 64;
    const size_t hb  = (size_t)b * SEQ * D_MODEL + h * HDK;
    const size_t vhb = (size_t)(b * NHEAD + h) * HDK;

    const int qrow = q0 + w * 16 + lm;         // this lane's q-row

    // Q fragments (B-operand: B[k=d][n=q], lane = q)
    bf16x8 Qf0, Qf1;
    {
        const unsigned short* qp = Q + hb + (size_t)qrow * D_MODEL + quad * 8;
        Qf0 = *(const bf16x8*)qp;
        Qf1 = *(const bf16x8*)(qp + 32);
    }

    f32x4 Oacc[4];                             // O^T: [d-tile][reg], lane = q
    #pragma unroll
    for (int nt = 0; nt < 4; ++nt) Oacc[nt] = (f32x4){0.f, 0.f, 0.f, 0.f};
    float m_run = -INFINITY, l_run = 0.f;      // scalar per lane (one q-row)

    const int srow = t >> 2;                   // staging row 0..63
    const int c0   = t & 3;                    // 2 16B slots per thread
    const unsigned short* kp = K + hb + (size_t)srow * D_MODEL + c0 * 16;
    const unsigned short* vp = VT + (vhb + srow) * SEQ + c0 * 16;

    float4 k0r = *(const float4*)kp;
    float4 k1r = *(const float4*)(kp + 8);
    float4 v0r = *(const float4*)vp;
    float4 v1r = *(const float4*)(vp + 8);

    unsigned short* ps = &Ps[w * 16 * 72];

    for (int kt = 0; kt <= qt; ++kt) {
        const int k0 = kt * 64;
        __syncthreads();
        *(float4*)&Ks[srow * 72 + c0 * 16]     = k0r;
        *(float4*)&Ks[srow * 72 + c0 * 16 + 8] = k1r;
        *(float4*)&Vs[srow * 72 + c0 * 16]     = v0r;
        *(float4*)&Vs[srow * 72 + c0 * 16 + 8] = v1r;
        if (kt < qt) {
            k0r = *(const float4*)(kp + (size_t)(k0 + 64) * D_MODEL);
            k1r = *(const float4*)(kp + (size_t)(k0 + 64) * D_MODEL + 8);
            v0r = *(const float4*)(vp + k0 + 64);
            v1r = *(const float4*)(vp + k0 + 64 + 8);
        }
        __syncthreads();

        // ---- S^T = K Q^T  (D[kv][q], lane holds q=lm, kv = ct*16+quad*4+r) ----
        f32x4 S[4];
        #pragma unroll
        for (int ct = 0; ct < 4; ++ct) {
            bf16x8 a0 = *(const bf16x8*)&Ks[(ct * 16 + lm) * 72 + quad * 8];
            bf16x8 a1 = *(const bf16x8*)&Ks[(ct * 16 + lm) * 72 + 32 + quad * 8];
            f32x4 z = (f32x4){0.f, 0.f, 0.f, 0.f};
            z = __builtin_amdgcn_mfma_f32_16x16x32_bf16(a0, Qf0, z, 0, 0, 0);
            z = __builtin_amdgcn_mfma_f32_16x16x32_bf16(a1, Qf1, z, 0, 0, 0);
            S[ct] = z;
        }

        // causal mask (diagonal tile only: kv tile straddles this wave's rows)
        if (k0 + 63 > q0 + w * 16) {
            #pragma unroll
            for (int ct = 0; ct < 4; ++ct)
                #pragma unroll
                for (int r = 0; r < 4; ++r)
                    if ((k0 + ct * 16 + quad * 4 + r) > qrow)
                        S[ct][r] = -1e30f;
        }

        // ---- online softmax (scalar state; reduce over quads: xor 16,32) ----
        float m = fmaxf(fmaxf(fmaxf(S[0][0], S[0][1]), fmaxf(S[0][2], S[0][3])),
                        fmaxf(fmaxf(S[1][0], S[1][1]), fmaxf(S[1][2], S[1][3])));
        m = fmaxf(m, fmaxf(fmaxf(fmaxf(S[2][0], S[2][1]), fmaxf(S[2][2], S[2][3])),
                           fmaxf(fmaxf(S[3][0], S[3][1]), fmaxf(S[3][2], S[3][3]))));
        m = fmaxf(m, __shfl_xor(m, 16));
        m = fmaxf(m, __shfl_xor(m, 32));
        const float m_new = fmaxf(m_run, m);
        const float alpha = __expf(m_run - m_new);
        m_run = m_new;
        float psum = 0.f;
        #pragma unroll
        for (int ct = 0; ct < 4; ++ct)
            #pragma unroll
            for (int r = 0; r < 4; ++r) {
                float e = __expf(S[ct][r] - m_new);
                S[ct][r] = e;
                psum += e;
            }
        psum += __shfl_xor(psum, 16);
        psum += __shfl_xor(psum, 32);
        l_run = l_run * alpha + psum;

        // ---- P^T -> wave-private LDS slab [q=lm][kv], then B-frag reads ----
        #pragma unroll
        for (int ct = 0; ct < 4; ++ct) {
            ushort4 pk = make_ushort4(f2bf(S[ct][0]), f2bf(S[ct][1]),
                                      f2bf(S[ct][2]), f2bf(S[ct][3]));
            *(ushort4*)&ps[lm * 72 + ct * 16 + quad * 4] = pk;
        }
        bf16x8 Pb0 = *(const bf16x8*)&ps[lm * 72 + quad * 8];
        bf16x8 Pb1 = *(const bf16x8*)&ps[lm * 72 + 32 + quad * 8];

        // ---- O^T = O^T*alpha + V^T P^T ----
        #pragma unroll
        for (int nt = 0; nt < 4; ++nt) {
            bf16x8 a0 = *(const bf16x8*)&Vs[(nt * 16 + lm) * 72 + quad * 8];
            bf16x8 a1 = *(const bf16x8*)&Vs[(nt * 16 + lm) * 72 + 32 + quad * 8];
            f32x4 o = Oacc[nt];
            #pragma unroll
            for (int r = 0; r < 4; ++r) o[r] *= alpha;
            o = __builtin_amdgcn_mfma_f32_16x16x32_bf16(a0, Pb0, o, 0, 0, 0);
            o = __builtin_amdgcn_mfma_f32_16x16x32_bf16(a1, Pb1, o, 0, 0, 0);
            Oacc[nt] = o;
        }
    }

    // ---- epilogue: O^T/l -> P slab [q][d] bf16 -> coalesced global stores ----
    const float inv_l = 1.f / l_run;
    #pragma unroll
    for (int nt = 0; nt < 4; ++nt) {
        ushort4 pk = make_ushort4(f2bf(Oacc[nt][0] * inv_l), f2bf(Oacc[nt][1] * inv_l),
                                  f2bf(Oacc[nt][2] * inv_l), f2bf(Oacc[nt][3] * inv_l));
        *(ushort4*)&ps[lm * 72 + nt * 16 + quad * 4] = pk;
    }
    #pragma unroll
    for (int p = 0; p < 2; ++p) {
        int qr = p * 8 + (L >> 3);             // row within wave's 16
        int dc = (L & 7) * 8;                  // 8 bf16 chunk
        uint4 val = *(const uint4*)&ps[qr * 72 + dc];
        *(uint4*)&A[hb + (size_t)(q0 + w * 16 + qr) * D_MODEL + dc] = val;
    }
}

// ---------------------------------------------------------------------------
extern "C" void kernel_launch(void* const* d_in, const int* in_sizes, int n_in,
                              void* d_out, int out_size, void* d_ws, size_t ws_size,
                              hipStream_t stream) {
    const float* q  = (const float*)d_in[0];
    const float* k  = (const float*)d_in[1];
    const float* v  = (const float*)d_in[2];
    const float* Wq = (const float*)d_in[4];
    const float* Wk = (const float*)d_in[5];
    const float* Wv = (const float*)d_in[6];
    const float* Wo = (const float*)d_in[7];
    float* out = (float*)d_out;

    char* ws = (char*)d_ws;
    const size_t MB = 1024 * 1024;
    unsigned short* qb  = (unsigned short*)(ws + 0 * MB);
    unsigned short* kb  = (unsigned short*)(ws + 8 * MB);
    unsigned short* vb  = (unsigned short*)(ws + 16 * MB);
    unsigned short* wqb = (unsigned short*)(ws + 24 * MB);
    unsigned short* wkb = (unsigned short*)(ws + 26 * MB);
    unsigned short* wvb = (unsigned short*)(ws + 28 * MB);
    unsigned short* wob = (unsigned short*)(ws + 30 * MB);
    unsigned short* Qp  = (unsigned short*)(ws + 32 * MB);
    unsigned short* Kp  = (unsigned short*)(ws + 40 * MB);
    unsigned short* VTp = (unsigned short*)(ws + 48 * MB);
    unsigned short* Ap  = (unsigned short*)(ws + 56 * MB);

    const int nX8 = BS * D_MODEL / 8;
    const int nW8 = D_MODEL * D_MODEL / 8;
    cast_act<<<dim3(nX8 / 256, 3), 256, 0, stream>>>(q, k, v, qb, kb, vb, nX8);
    cast_wt <<<dim3(nW8 / 256, 4), 256, 0, stream>>>(Wq, Wk, Wv, Wo, wqb, wkb, wvb, wob, nW8);

    proj_gemm<<<dim3(D_MODEL / 128, BS / 128, 3), 256, 0, stream>>>(
        qb, kb, vb, wqb, wkb, wvb, Qp, Kp, VTp);

    attn_mfma<<<dim3(SEQ / 64, NHEAD, BATCH), 256, 0, stream>>>(Qp, Kp, VTp, Ap);

    out_gemm<<<dim3(D_MODEL / 128, BS / 128), 256, 0, stream>>>(Ap, wob, out);
}

// Round 5
// 225.911 us; speedup vs baseline: 8.1300x; 1.1055x over previous
//
#include <hip/hip_runtime.h>
#include <hip/hip_bf16.h>

#define D_MODEL 1024
#define NHEAD   16
#define HDK     64
#define SEQ     2048
#define BATCH   2
#define BS      (BATCH * SEQ)

typedef __attribute__((ext_vector_type(8))) short bf16x8;
typedef __attribute__((ext_vector_type(4))) float f32x4;

__device__ __forceinline__ unsigned short f2bf(float f) {
    unsigned u = __builtin_bit_cast(unsigned, f);
    u += 0x7fffu + ((u >> 16) & 1u);          // round-to-nearest-even
    return (unsigned short)(u >> 16);
}

// pack hi16(x):hi16(y) -> (hi16(y)<<16)|hi16(x) with one v_perm_b32 (truncation)
__device__ __forceinline__ unsigned pack_hi(float x, float y) {
    return __builtin_amdgcn_perm(__builtin_bit_cast(unsigned, y),
                                 __builtin_bit_cast(unsigned, x), 0x07060302u);
}

typedef const void __attribute__((address_space(1))) gas_void;
typedef void __attribute__((address_space(3))) las_void;

__device__ __forceinline__ void gll16(const void* g, void* l) {
    __builtin_amdgcn_global_load_lds((gas_void*)g, (las_void*)l, 16, 0, 0);
}

// ---------------------------------------------------------------------------
// fp32 -> bf16 casts
// ---------------------------------------------------------------------------
__device__ __forceinline__ void cast_body(const float* __restrict__ src,
                                          unsigned short* __restrict__ dst, int i) {
    const float4* p = (const float4*)src + (size_t)i * 2;
    float4 a = p[0], b = p[1];
    ushort4 lo = make_ushort4(f2bf(a.x), f2bf(a.y), f2bf(a.z), f2bf(a.w));
    ushort4 hi = make_ushort4(f2bf(b.x), f2bf(b.y), f2bf(b.z), f2bf(b.w));
    ushort4* q = (ushort4*)dst + (size_t)i * 2;
    q[0] = lo; q[1] = hi;
}

__global__ __launch_bounds__(256)
void cast_act(const float* a, const float* b, const float* c,
              unsigned short* oa, unsigned short* ob, unsigned short* oc, int n8) {
    int i = blockIdx.x * 256 + threadIdx.x;
    if (i >= n8) return;
    const float* s = blockIdx.y == 0 ? a : blockIdx.y == 1 ? b : c;
    unsigned short* d = blockIdx.y == 0 ? oa : blockIdx.y == 1 ? ob : oc;
    cast_body(s, d, i);
}

__global__ __launch_bounds__(256)
void cast_wt(const float* a, const float* b, const float* c, const float* dd,
             unsigned short* oa, unsigned short* ob, unsigned short* oc, unsigned short* od, int n8) {
    int i = blockIdx.x * 256 + threadIdx.x;
    if (i >= n8) return;
    const float* s = blockIdx.y == 0 ? a : blockIdx.y == 1 ? b : blockIdx.y == 2 ? c : dd;
    unsigned short* d = blockIdx.y == 0 ? oa : blockIdx.y == 1 ? ob : blockIdx.y == 2 ? oc : od;
    cast_body(s, d, i);
}

// ---------------------------------------------------------------------------
// GEMM K-loop, BM=128 BN=128 BK=64, 256 thr, wave -> 64x64 quadrant.
// ---------------------------------------------------------------------------
__device__ __forceinline__ void gemm_kloop128(const unsigned short* __restrict__ X,
                                              const unsigned short* __restrict__ W,
                                              unsigned short* As, unsigned short* Bs,
                                              int bm, int bn, f32x4 acc[4][4]) {
    const int t    = threadIdx.x;
    const int w    = t >> 6;
    const int L    = t & 63;
    const int quad = L >> 4;
    const int lm   = L & 15;
    const int r8   = L >> 3;
    const int sl   = L & 7;
    const int xcol = ((sl ^ r8) & 7) * 8;
    const int wr   = (w >> 1) * 64;
    const int wc   = (w & 1) * 64;

    for (int kt = 0; kt < D_MODEL; kt += 64) {
        __syncthreads();
        #pragma unroll
        for (int i = 0; i < 4; ++i) {
            int c = w * 4 + i;
            gll16(X + (size_t)(bm + c * 8 + r8) * D_MODEL + kt + xcol, &As[c * 512]);
        }
        #pragma unroll
        for (int i = 0; i < 4; ++i) {
            int c = w * 4 + i;
            gll16(W + (size_t)(bn + c * 8 + r8) * D_MODEL + kt + xcol, &Bs[c * 512]);
        }
        __syncthreads();

        #pragma unroll
        for (int ch = 0; ch < 2; ++ch) {
            bf16x8 af[4], bfr[4];
            #pragma unroll
            for (int ms = 0; ms < 4; ++ms) {
                int row = wr + ms * 16 + lm;
                af[ms] = *(const bf16x8*)&As[row * 64 + (((ch * 4 + quad) ^ (row & 7)) * 8)];
            }
            #pragma unroll
            for (int ns = 0; ns < 4; ++ns) {
                int row = wc + ns * 16 + lm;
                bfr[ns] = *(const bf16x8*)&Bs[row * 64 + (((ch * 4 + quad) ^ (row & 7)) * 8)];
            }
            #pragma unroll
            for (int ms = 0; ms < 4; ++ms)
                #pragma unroll
                for (int ns = 0; ns < 4; ++ns)
                    acc[ms][ns] = __builtin_amdgcn_mfma_f32_16x16x32_bf16(
                        af[ms], bfr[ns], acc[ms][ns], 0, 0, 0);
        }
    }
}

// BM=128 BN=64 variant (more blocks for the small out_gemm)
__device__ __forceinline__ void gemm_kloop64(const unsigned short* __restrict__ X,
                                             const unsigned short* __restrict__ W,
                                             unsigned short* As, unsigned short* Bs,
                                             int bm, int bn, f32x4 acc[2][4]) {
    const int t    = threadIdx.x;
    const int w    = t >> 6;
    const int L    = t & 63;
    const int quad = L >> 4;
    const int lm   = L & 15;
    const int r8   = L >> 3;
    const int sl   = L & 7;
    const int xcol = ((sl ^ r8) & 7) * 8;

    for (int kt = 0; kt < D_MODEL; kt += 64) {
        __syncthreads();
        #pragma unroll
        for (int i = 0; i < 4; ++i) {
            int c = w * 4 + i;
            gll16(X + (size_t)(bm + c * 8 + r8) * D_MODEL + kt + xcol, &As[c * 512]);
        }
        #pragma unroll
        for (int i = 0; i < 2; ++i) {
            int c = w * 2 + i;
            gll16(W + (size_t)(bn + c * 8 + r8) * D_MODEL + kt + xcol, &Bs[c * 512]);
        }
        __syncthreads();

        #pragma unroll
        for (int ch = 0; ch < 2; ++ch) {
            bf16x8 af[2], bfr[4];
            #pragma unroll
            for (int ms = 0; ms < 2; ++ms) {
                int row = w * 32 + ms * 16 + lm;
                af[ms] = *(const bf16x8*)&As[row * 64 + (((ch * 4 + quad) ^ (row & 7)) * 8)];
            }
            #pragma unroll
            for (int ns = 0; ns < 4; ++ns) {
                int row = ns * 16 + lm;
                bfr[ns] = *(const bf16x8*)&Bs[row * 64 + (((ch * 4 + quad) ^ (row & 7)) * 8)];
            }
            #pragma unroll
            for (int ms = 0; ms < 2; ++ms)
                #pragma unroll
                for (int ns = 0; ns < 4; ++ns)
                    acc[ms][ns] = __builtin_amdgcn_mfma_f32_16x16x32_bf16(
                        af[ms], bfr[ns], acc[ms][ns], 0, 0, 0);
        }
    }
}

// ---------------------------------------------------------------------------
// Fused Q/K/V projections. z=0: Q (x0.125, row-major), z=1: K (row-major),
// z=2: V transposed per head: VT[(b*16+h)*64+d][s].
// ---------------------------------------------------------------------------
__global__ __launch_bounds__(256, 3)
void proj_gemm(const unsigned short* __restrict__ qx, const unsigned short* __restrict__ kx,
               const unsigned short* __restrict__ vx, const unsigned short* __restrict__ wq,
               const unsigned short* __restrict__ wk, const unsigned short* __restrict__ wv,
               unsigned short* __restrict__ Qp, unsigned short* __restrict__ Kp,
               unsigned short* __restrict__ VT) {
    __shared__ __align__(16) unsigned short As[128 * 64];
    __shared__ __align__(16) unsigned short Bs[128 * 64];

    const int p = blockIdx.z;
    const unsigned short* X = p == 0 ? qx : p == 1 ? kx : vx;
    const unsigned short* W = p == 0 ? wq : p == 1 ? wk : wv;
    const int bm = blockIdx.y * 128, bn = blockIdx.x * 128;

    f32x4 acc[4][4];
    #pragma unroll
    for (int ms = 0; ms < 4; ++ms)
        #pragma unroll
        for (int ns = 0; ns < 4; ++ns)
            acc[ms][ns] = (f32x4){0.f, 0.f, 0.f, 0.f};

    gemm_kloop128(X, W, As, Bs, bm, bn, acc);

    const int t = threadIdx.x, w = t >> 6, L = t & 63, quad = L >> 4, lm = L & 15;
    const int wr = (w >> 1) * 64, wc = (w & 1) * 64;
    if (p == 2) {
        const int b    = bm >> 11;
        const int s_in = (bm & (SEQ - 1)) + wr;
        #pragma unroll
        for (int ms = 0; ms < 4; ++ms)
            #pragma unroll
            for (int ns = 0; ns < 4; ++ns) {
                int dg = bn + wc + ns * 16 + lm;
                int h  = dg >> 6, d = dg & 63;
                ushort4 pk = make_ushort4(f2bf(acc[ms][ns][0]), f2bf(acc[ms][ns][1]),
                                          f2bf(acc[ms][ns][2]), f2bf(acc[ms][ns][3]));
                *(ushort4*)&VT[((size_t)((b * NHEAD + h) * HDK + d)) * SEQ +
                               s_in + ms * 16 + quad * 4] = pk;
            }
    } else {
        unsigned short* Y = p == 0 ? Qp : Kp;
        const float scl = p == 0 ? 0.125f : 1.0f;
        #pragma unroll
        for (int ms = 0; ms < 4; ++ms)
            #pragma unroll
            for (int ns = 0; ns < 4; ++ns)
                #pragma unroll
                for (int r = 0; r < 4; ++r)
                    Y[(size_t)(bm + wr + ms * 16 + quad * 4 + r) * D_MODEL +
                      bn + wc + ns * 16 + lm] = f2bf(acc[ms][ns][r] * scl);
    }
}

__global__ __launch_bounds__(256)
void out_gemm(const unsigned short* __restrict__ X, const unsigned short* __restrict__ W,
              float* __restrict__ Y) {
    __shared__ __align__(16) unsigned short As[128 * 64];
    __shared__ __align__(16) unsigned short Bs[64 * 64];
    const int bm = blockIdx.y * 128, bn = blockIdx.x * 64;

    f32x4 acc[2][4];
    #pragma unroll
    for (int ms = 0; ms < 2; ++ms)
        #pragma unroll
        for (int ns = 0; ns < 4; ++ns)
            acc[ms][ns] = (f32x4){0.f, 0.f, 0.f, 0.f};

    gemm_kloop64(X, W, As, Bs, bm, bn, acc);

    const int t = threadIdx.x, w = t >> 6, L = t & 63, quad = L >> 4, lm = L & 15;
    #pragma unroll
    for (int ms = 0; ms < 2; ++ms)
        #pragma unroll
        for (int ns = 0; ns < 4; ++ns)
            #pragma unroll
            for (int r = 0; r < 4; ++r)
                Y[(size_t)(bm + w * 32 + ms * 16 + quad * 4 + r) * D_MODEL +
                  bn + ns * 16 + lm] = acc[ms][ns][r];
}

// ---------------------------------------------------------------------------
// Flash attention, causal, S^T formulation, paired q-tiles for perfect
// balance: block px handles qt = px then qt = 31-px (33 tiles total each).
// LDS double-buffered K/V -> ONE barrier per tile. 256 thr = 4 waves x 16 q.
// ---------------------------------------------------------------------------
__global__ __launch_bounds__(256, 3)
void attn_mfma(const unsigned short* __restrict__ Q, const unsigned short* __restrict__ K,
               const unsigned short* __restrict__ VT, unsigned short* __restrict__ A) {
    __shared__ __align__(16) unsigned short Ks[2][64 * 72];   // [buf][kv][d]
    __shared__ __align__(16) unsigned short Vs[2][64 * 72];   // [buf][d][kv]
    __shared__ __align__(16) unsigned short Ps[4 * 16 * 72];  // per-wave P^T slabs

    const int t    = threadIdx.x;
    const int w    = t >> 6;
    const int L    = t & 63;
    const int quad = L >> 4;
    const int lm   = L & 15;
    const int h    = blockIdx.y;
    const int b    = blockIdx.z;
    const size_t hb  = (size_t)b * SEQ * D_MODEL + h * HDK;
    const size_t vhb = (size_t)(b * NHEAD + h) * HDK;

    const int srow = t >> 2;                 // staging row 0..63
    const int sc   = (t & 3) * 16;           // element offset of this thread's 2 slots
    const unsigned short* kp = K + hb + (size_t)srow * D_MODEL + sc;
    const unsigned short* vp = VT + (vhb + srow) * SEQ + sc;
    unsigned short* ps = &Ps[w * 16 * 72];

    for (int half = 0; half < 2; ++half) {
        const int qt   = half ? 31 - (int)blockIdx.x : (int)blockIdx.x;
        const int q0   = qt * 64;
        const int qrow = q0 + w * 16 + lm;

        // Q fragments (B-operand), registers for this half
        bf16x8 Qf0, Qf1;
        {
            const unsigned short* qp = Q + hb + (size_t)qrow * D_MODEL + quad * 8;
            Qf0 = *(const bf16x8*)qp;
            Qf1 = *(const bf16x8*)(qp + 32);
        }

        f32x4 Oacc[4];
        #pragma unroll
        for (int nt = 0; nt < 4; ++nt) Oacc[nt] = (f32x4){0.f, 0.f, 0.f, 0.f};
        float m_run = -INFINITY, l_run = 0.f;

        // prologue: tile 0 -> buf 0; prefetch tile 1 into regs
        float4 kr0 = *(const float4*)kp;
        float4 kr1 = *(const float4*)(kp + 8);
        float4 vr0 = *(const float4*)vp;
        float4 vr1 = *(const float4*)(vp + 8);
        *(float4*)&Ks[0][srow * 72 + sc]     = kr0;
        *(float4*)&Ks[0][srow * 72 + sc + 8] = kr1;
        *(float4*)&Vs[0][srow * 72 + sc]     = vr0;
        *(float4*)&Vs[0][srow * 72 + sc + 8] = vr1;
        if (qt >= 1) {
            kr0 = *(const float4*)(kp + (size_t)64 * D_MODEL);
            kr1 = *(const float4*)(kp + (size_t)64 * D_MODEL + 8);
            vr0 = *(const float4*)(vp + 64);
            vr1 = *(const float4*)(vp + 64 + 8);
        }
        __syncthreads();

        int bb = 0;
        for (int kt = 0; kt <= qt; ++kt) {
            const int k0 = kt * 64;
            const unsigned short* Kc = Ks[bb];
            const unsigned short* Vc = Vs[bb];
            if (kt < qt) {                      // stage kt+1 into other buffer
                unsigned short* Kn = Ks[bb ^ 1];
                unsigned short* Vn = Vs[bb ^ 1];
                *(float4*)&Kn[srow * 72 + sc]     = kr0;
                *(float4*)&Kn[srow * 72 + sc + 8] = kr1;
                *(float4*)&Vn[srow * 72 + sc]     = vr0;
                *(float4*)&Vn[srow * 72 + sc + 8] = vr1;
                if (kt + 2 <= qt) {             // prefetch kt+2
                    kr0 = *(const float4*)(kp + (size_t)(k0 + 128) * D_MODEL);
                    kr1 = *(const float4*)(kp + (size_t)(k0 + 128) * D_MODEL + 8);
                    vr0 = *(const float4*)(vp + k0 + 128);
                    vr1 = *(const float4*)(vp + k0 + 128 + 8);
                }
            }

            // ---- S^T = K Q^T (lane owns q-row lm; kv = ct*16+quad*4+r) ----
            f32x4 S[4];
            #pragma unroll
            for (int ct = 0; ct < 4; ++ct) {
                bf16x8 a0 = *(const bf16x8*)&Kc[(ct * 16 + lm) * 72 + quad * 8];
                bf16x8 a1 = *(const bf16x8*)&Kc[(ct * 16 + lm) * 72 + 32 + quad * 8];
                f32x4 z = (f32x4){0.f, 0.f, 0.f, 0.f};
                z = __builtin_amdgcn_mfma_f32_16x16x32_bf16(a0, Qf0, z, 0, 0, 0);
                z = __builtin_amdgcn_mfma_f32_16x16x32_bf16(a1, Qf1, z, 0, 0, 0);
                S[ct] = z;
            }

            // causal mask (diag-straddling tiles only)
            if (k0 + 63 > q0 + w * 16) {
                #pragma unroll
                for (int ct = 0; ct < 4; ++ct)
                    #pragma unroll
                    for (int r = 0; r < 4; ++r)
                        if ((k0 + ct * 16 + quad * 4 + r) > qrow)
                            S[ct][r] = -1e30f;
            }

            // ---- online softmax (scalar per-lane state) ----
            float m = fmaxf(fmaxf(fmaxf(S[0][0], S[0][1]), fmaxf(S[0][2], S[0][3])),
                            fmaxf(fmaxf(S[1][0], S[1][1]), fmaxf(S[1][2], S[1][3])));
            m = fmaxf(m, fmaxf(fmaxf(fmaxf(S[2][0], S[2][1]), fmaxf(S[2][2], S[2][3])),
                               fmaxf(fmaxf(S[3][0], S[3][1]), fmaxf(S[3][2], S[3][3]))));
            m = fmaxf(m, __shfl_xor(m, 16));
            m = fmaxf(m, __shfl_xor(m, 32));
            const float m_new = fmaxf(m_run, m);
            const float alpha = __expf(m_run - m_new);
            m_run = m_new;
            float psum = 0.f;
            #pragma unroll
            for (int ct = 0; ct < 4; ++ct)
                #pragma unroll
                for (int r = 0; r < 4; ++r) {
                    float e = __expf(S[ct][r] - m_new);
                    S[ct][r] = e;
                    psum += e;
                }
            psum += __shfl_xor(psum, 16);
            psum += __shfl_xor(psum, 32);
            l_run = l_run * alpha + psum;

            // ---- P^T -> wave-private slab (v_perm truncation pack) ----
            #pragma unroll
            for (int ct = 0; ct < 4; ++ct) {
                uint2 pw = make_uint2(pack_hi(S[ct][0], S[ct][1]),
                                      pack_hi(S[ct][2], S[ct][3]));
                *(uint2*)&ps[lm * 72 + ct * 16 + quad * 4] = pw;
            }
            bf16x8 Pb0 = *(const bf16x8*)&ps[lm * 72 + quad * 8];
            bf16x8 Pb1 = *(const bf16x8*)&ps[lm * 72 + 32 + quad * 8];

            // ---- O^T = O^T*alpha + V^T P^T ----
            #pragma unroll
            for (int nt = 0; nt < 4; ++nt) {
                bf16x8 a0 = *(const bf16x8*)&Vc[(nt * 16 + lm) * 72 + quad * 8];
                bf16x8 a1 = *(const bf16x8*)&Vc[(nt * 16 + lm) * 72 + 32 + quad * 8];
                f32x4 o = Oacc[nt];
                #pragma unroll
                for (int r = 0; r < 4; ++r) o[r] *= alpha;
                o = __builtin_amdgcn_mfma_f32_16x16x32_bf16(a0, Pb0, o, 0, 0, 0);
                o = __builtin_amdgcn_mfma_f32_16x16x32_bf16(a1, Pb1, o, 0, 0, 0);
                Oacc[nt] = o;
            }

            __syncthreads();                   // single barrier per tile
            bb ^= 1;
        }

        // ---- epilogue: O^T/l -> slab [q][d] -> coalesced stores ----
        const float inv_l = 1.f / l_run;
        #pragma unroll
        for (int nt = 0; nt < 4; ++nt) {
            ushort4 pk = make_ushort4(f2bf(Oacc[nt][0] * inv_l), f2bf(Oacc[nt][1] * inv_l),
                                      f2bf(Oacc[nt][2] * inv_l), f2bf(Oacc[nt][3] * inv_l));
            *(ushort4*)&ps[lm * 72 + nt * 16 + quad * 4] = pk;
        }
        #pragma unroll
        for (int p = 0; p < 2; ++p) {
            int qr = p * 8 + (L >> 3);
            int dc = (L & 7) * 8;
            uint4 val = *(const uint4*)&ps[qr * 72 + dc];
            *(uint4*)&A[hb + (size_t)(q0 + w * 16 + qr) * D_MODEL + dc] = val;
        }
    }
}

// ---------------------------------------------------------------------------
extern "C" void kernel_launch(void* const* d_in, const int* in_sizes, int n_in,
                              void* d_out, int out_size, void* d_ws, size_t ws_size,
                              hipStream_t stream) {
    const float* q  = (const float*)d_in[0];
    const float* k  = (const float*)d_in[1];
    const float* v  = (const float*)d_in[2];
    const float* Wq = (const float*)d_in[4];
    const float* Wk = (const float*)d_in[5];
    const float* Wv = (const float*)d_in[6];
    const float* Wo = (const float*)d_in[7];
    float* out = (float*)d_out;

    char* ws = (char*)d_ws;
    const size_t MB = 1024 * 1024;
    unsigned short* qb  = (unsigned short*)(ws + 0 * MB);
    unsigned short* kb  = (unsigned short*)(ws + 8 * MB);
    unsigned short* vb  = (unsigned short*)(ws + 16 * MB);
    unsigned short* wqb = (unsigned short*)(ws + 24 * MB);
    unsigned short* wkb = (unsigned short*)(ws + 26 * MB);
    unsigned short* wvb = (unsigned short*)(ws + 28 * MB);
    unsigned short* wob = (unsigned short*)(ws + 30 * MB);
    unsigned short* Qp  = (unsigned short*)(ws + 32 * MB);
    unsigned short* Kp  = (unsigned short*)(ws + 40 * MB);
    unsigned short* VTp = (unsigned short*)(ws + 48 * MB);
    unsigned short* Ap  = (unsigned short*)(ws + 56 * MB);

    const int nX8 = BS * D_MODEL / 8;
    const int nW8 = D_MODEL * D_MODEL / 8;
    cast_act<<<dim3(nX8 / 256, 3), 256, 0, stream>>>(q, k, v, qb, kb, vb, nX8);
    cast_wt <<<dim3(nW8 / 256, 4), 256, 0, stream>>>(Wq, Wk, Wv, Wo, wqb, wkb, wvb, wob, nW8);

    proj_gemm<<<dim3(D_MODEL / 128, BS / 128, 3), 256, 0, stream>>>(
        qb, kb, vb, wqb, wkb, wvb, Qp, Kp, VTp);

    attn_mfma<<<dim3(16, NHEAD, BATCH), 256, 0, stream>>>(Qp, Kp, VTp, Ap);

    out_gemm<<<dim3(D_MODEL / 64, BS / 128), 256, 0, stream>>>(Ap, wob, out);
}